// Round 1
// baseline (437.864 us; speedup 1.0000x reference)
//
#include <hip/hip_runtime.h>

#define E_TOTAL   800000
#define HID       128
#define EPB       256
#define LN_EPS    1e-5f

typedef __attribute__((ext_vector_type(8)))  short bs8;
typedef __attribute__((ext_vector_type(16))) float fx16;

__device__ __forceinline__ float bf2f(unsigned short u) {
    union { unsigned int i; float f; } c; c.i = ((unsigned int)u) << 16; return c.f;
}
__device__ __forceinline__ unsigned short f2bf(float f) {
    union { float f; unsigned int i; } c; c.f = f;
    unsigned int r = c.i + 0x7FFFu + ((c.i >> 16) & 1u);
    return (unsigned short)(r >> 16);
}
__device__ __forceinline__ float fast_tanh(float x) {
    float e = __expf(2.0f * x);
    return 1.0f - __fdividef(2.0f, e + 1.0f);
}

// ---- prep 1: W -> MFMA A-fragment-linear bf16, A = W^T (M=fout, K=fin) ----
// frag fr = L*32 + rt*8 + ks ; lane l ; 8 bf16 = W[fi0+j][fo],
// fo = rt*32 + (l&31), fi0 = ks*16 + (l>>5)*8
__global__ void prep_wfrag(const float* __restrict__ Ws, unsigned short* __restrict__ wf) {
    int t = blockIdx.x * blockDim.x + threadIdx.x;
    if (t >= 3*4*8*64) return;
    int l  = t & 63;
    int fr = t >> 6;
    int ks = fr & 7;
    int rt = (fr >> 3) & 3;
    int L  = fr >> 5;
    int fo  = rt*32 + (l & 31);
    int fi0 = ks*16 + ((l >> 5) << 3);
    const float* src = Ws + L*HID*HID;
    unsigned short tmp[8];
    #pragma unroll
    for (int j = 0; j < 8; ++j) tmp[j] = f2bf(src[(fi0 + j)*HID + fo]);
    *reinterpret_cast<bs8*>(wf + t*8) = *reinterpret_cast<const bs8*>(tmp);
}

// ---- prep 2: constants reordered to C-fragment order ----
// T[L][c][128] for c in {b,gamma,beta}, then wout[128] at offset 1152.
// within 128: idx = rt*32 + h*16 + reg ; fout = rt*32 + (reg&3) + 8*(reg>>2) + 4*h
__global__ void prep_tab(const float* __restrict__ bs, const float* __restrict__ gammas,
                         const float* __restrict__ betas, const float* __restrict__ w_out,
                         unsigned short* __restrict__ T) {
    int t = blockIdx.x * blockDim.x + threadIdx.x;
    if (t >= 1280) return;
    int reg = t & 15, h = (t >> 4) & 1, rt = (t >> 5) & 3;
    int fout = rt*32 + (reg & 3) + 8*(reg >> 2) + 4*h;
    float v;
    if (t < 1152) {
        int L = t / 384;
        int c = (t / 128) % 3;
        const float* src = (c == 0) ? bs : ((c == 1) ? gammas : betas);
        v = src[L*HID + fout];
    } else {
        v = w_out[fout];
    }
    T[t] = f2bf(v);
}

// ---- fused main kernel ----
__launch_bounds__(256, 1)
__global__ void edge_fused(const float* __restrict__ x,
                           const int* __restrict__ eidx,
                           const unsigned short* __restrict__ wf,
                           const unsigned short* __restrict__ T,
                           const float* __restrict__ b_out,
                           float* __restrict__ out)
{
    __shared__ __align__(16) unsigned short hA[EPB*HID];     // 64 KB, XOR-swizzled rows
    __shared__ __align__(16) unsigned short Wlds[HID*HID];   // 32 KB, frag-linear
    __shared__ int idx_s[2*EPB];                             // 2 KB

    const int t  = threadIdx.x;
    const int l  = t & 63;
    const int w  = t >> 6;
    const int eb = blockIdx.x * EPB;
    const int l31 = l & 31;
    const int h   = l >> 5;
    const int hh  = h << 4;

    idx_s[2*t]     = eidx[eb + t];
    idx_s[2*t + 1] = eidx[E_TOTAL + eb + t];
    __syncthreads();

    // gather: wave w loads node rows for its own edges (rows w*128 .. w*128+127, row=2e+half)
    // 16 lanes cooperatively read one 256B node row (fully coalesced)
    #pragma unroll 8
    for (int i = 0; i < 32; ++i) {
        int r = w*128 + i*4 + (l >> 4);
        int node = idx_s[r];
        const float4 v = *(reinterpret_cast<const float4*>(x + node*64) + (l & 15));
        ushort4 p;
        p.x = f2bf(v.x); p.y = f2bf(v.y); p.z = f2bf(v.z); p.w = f2bf(v.w);
        int e  = r >> 1;
        int cb = (r & 1)*128 + (l & 15)*8;
        *reinterpret_cast<ushort4*>(reinterpret_cast<char*>(hA) + e*256 + (cb ^ ((e & 7) << 4))) = p;
    }

    const int e0 = w*64 + l31;          // this wave's two edge columns per lane
    const int e1 = e0 + 32;
    const int sz0 = (e0 & 7) << 4;
    const int sz1 = (e1 & 7) << 4;

    float o0 = 0.f, o1 = 0.f;

    for (int L = 0; L < 3; ++L) {
        __syncthreads();   // prior Wlds readers done
        {
            const char* wsrc = reinterpret_cast<const char*>(wf + L*(HID*HID));
            #pragma unroll
            for (int i = 0; i < 8; ++i) {
                const void* g = wsrc + (size_t)(i*256 + t)*16;
                void* lp = reinterpret_cast<char*>(Wlds) + (i*256 + w*64)*16;
                __builtin_amdgcn_global_load_lds(
                    (const __attribute__((address_space(1))) unsigned int*)g,
                    (__attribute__((address_space(3))) unsigned int*)lp, 16, 0, 0);
            }
        }
        __syncthreads();   // Wlds staged (syncthreads drains vmcnt)

        fx16 acc[4][2];
        #pragma unroll
        for (int rt = 0; rt < 4; ++rt)
            #pragma unroll
            for (int n = 0; n < 2; ++n)
                #pragma unroll
                for (int j = 0; j < 16; ++j) acc[rt][n][j] = 0.f;

        // Ct = W^T (A) @ H^T (B): M=fout(4x32), N=edges(2x32), K=fin(8x16)
        #pragma unroll
        for (int ks = 0; ks < 8; ++ks) {
            const int cb = ks*32 + hh;
            bs8 b0 = *reinterpret_cast<const bs8*>(reinterpret_cast<const char*>(hA) + e0*256 + (cb ^ sz0));
            bs8 b1 = *reinterpret_cast<const bs8*>(reinterpret_cast<const char*>(hA) + e1*256 + (cb ^ sz1));
            #pragma unroll
            for (int rt = 0; rt < 4; ++rt) {
                bs8 a = *reinterpret_cast<const bs8*>(reinterpret_cast<const char*>(Wlds) + ((rt*8 + ks)*64 + l)*16);
                acc[rt][0] = __builtin_amdgcn_mfma_f32_32x32x16_bf16(a, b0, acc[rt][0], 0, 0, 0);
                acc[rt][1] = __builtin_amdgcn_mfma_f32_32x32x16_bf16(a, b1, acc[rt][1], 0, 0, 0);
            }
        }

        // ---- epilogue: +bias, LN stats (in-reg + one shfl_xor(32)), gamma/beta, tanh ----
        const unsigned short* Tb = T + (L*3 + 0)*128 + hh;
        const unsigned short* Tg = T + (L*3 + 1)*128 + hh;
        const unsigned short* Te = T + (L*3 + 2)*128 + hh;

        float s0 = 0.f, s1 = 0.f, q0 = 0.f, q1 = 0.f;
        #pragma unroll
        for (int rt = 0; rt < 4; ++rt) {
            bs8 blo = *reinterpret_cast<const bs8*>(Tb + rt*32);
            bs8 bhi = *reinterpret_cast<const bs8*>(Tb + rt*32 + 8);
            #pragma unroll
            for (int j = 0; j < 16; ++j) {
                float bv = bf2f((unsigned short)(j < 8 ? blo[j] : bhi[j-8]));
                float a0 = acc[rt][0][j] + bv;
                float a1 = acc[rt][1][j] + bv;
                acc[rt][0][j] = a0; acc[rt][1][j] = a1;
                s0 += a0; q0 += a0*a0;
                s1 += a1; q1 += a1*a1;
            }
        }
        s0 += __shfl_xor(s0, 32); q0 += __shfl_xor(q0, 32);
        s1 += __shfl_xor(s1, 32); q1 += __shfl_xor(q1, 32);
        const float mu0 = s0 * (1.f/128.f), mu1 = s1 * (1.f/128.f);
        const float r0 = rsqrtf(q0*(1.f/128.f) - mu0*mu0 + LN_EPS);
        const float r1 = rsqrtf(q1*(1.f/128.f) - mu1*mu1 + LN_EPS);

        if (L < 2) {
            #pragma unroll
            for (int rt = 0; rt < 4; ++rt) {
                bs8 glo = *reinterpret_cast<const bs8*>(Tg + rt*32);
                bs8 ghi = *reinterpret_cast<const bs8*>(Tg + rt*32 + 8);
                bs8 elo = *reinterpret_cast<const bs8*>(Te + rt*32);
                bs8 ehi = *reinterpret_cast<const bs8*>(Te + rt*32 + 8);
                float v0[16], v1[16];
                #pragma unroll
                for (int j = 0; j < 16; ++j) {
                    float gv = bf2f((unsigned short)(j < 8 ? glo[j] : ghi[j-8]));
                    float ev = bf2f((unsigned short)(j < 8 ? elo[j] : ehi[j-8]));
                    v0[j] = fast_tanh((acc[rt][0][j] - mu0)*r0*gv + ev);
                    v1[j] = fast_tanh((acc[rt][1][j] - mu1)*r1*gv + ev);
                }
                #pragma unroll
                for (int qd = 0; qd < 4; ++qd) {
                    ushort4 p0, p1;
                    p0.x = f2bf(v0[qd*4+0]); p0.y = f2bf(v0[qd*4+1]);
                    p0.z = f2bf(v0[qd*4+2]); p0.w = f2bf(v0[qd*4+3]);
                    p1.x = f2bf(v1[qd*4+0]); p1.y = f2bf(v1[qd*4+1]);
                    p1.z = f2bf(v1[qd*4+2]); p1.w = f2bf(v1[qd*4+3]);
                    int cb = rt*64 + qd*16 + (h << 3);   // fout = rt*32 + 8*qd + 4*h + m
                    *reinterpret_cast<ushort4*>(reinterpret_cast<char*>(hA) + e0*256 + (cb ^ sz0)) = p0;
                    *reinterpret_cast<ushort4*>(reinterpret_cast<char*>(hA) + e1*256 + (cb ^ sz1)) = p1;
                }
            }
        } else {
            const unsigned short* Tw = T + 1152 + hh;
            #pragma unroll
            for (int rt = 0; rt < 4; ++rt) {
                bs8 glo = *reinterpret_cast<const bs8*>(Tg + rt*32);
                bs8 ghi = *reinterpret_cast<const bs8*>(Tg + rt*32 + 8);
                bs8 elo = *reinterpret_cast<const bs8*>(Te + rt*32);
                bs8 ehi = *reinterpret_cast<const bs8*>(Te + rt*32 + 8);
                bs8 wlo = *reinterpret_cast<const bs8*>(Tw + rt*32);
                bs8 whi = *reinterpret_cast<const bs8*>(Tw + rt*32 + 8);
                #pragma unroll
                for (int j = 0; j < 16; ++j) {
                    float gv = bf2f((unsigned short)(j < 8 ? glo[j] : ghi[j-8]));
                    float ev = bf2f((unsigned short)(j < 8 ? elo[j] : ehi[j-8]));
                    float wv = bf2f((unsigned short)(j < 8 ? wlo[j] : whi[j-8]));
                    o0 += fast_tanh((acc[rt][0][j] - mu0)*r0*gv + ev) * wv;
                    o1 += fast_tanh((acc[rt][1][j] - mu1)*r1*gv + ev) * wv;
                }
            }
        }
    }

    o0 += __shfl_xor(o0, 32);
    o1 += __shfl_xor(o1, 32);
    if (l < 32) {
        const float bo = b_out[0];
        out[eb + w*64 + l]      = o0 + bo;
        out[eb + w*64 + 32 + l] = o1 + bo;
    }
}

extern "C" void kernel_launch(void* const* d_in, const int* in_sizes, int n_in,
                              void* d_out, int out_size, void* d_ws, size_t ws_size,
                              hipStream_t stream) {
    const float* x      = (const float*)d_in[0];
    const int*   eidx   = (const int*)d_in[1];
    const float* Ws     = (const float*)d_in[2];
    const float* bs     = (const float*)d_in[3];
    const float* gammas = (const float*)d_in[4];
    const float* betas  = (const float*)d_in[5];
    const float* w_out  = (const float*)d_in[6];
    const float* b_out  = (const float*)d_in[7];
    float* out = (float*)d_out;

    unsigned short* wf = (unsigned short*)d_ws;                       // 98304 B
    unsigned short* T  = (unsigned short*)((char*)d_ws + 3*HID*HID*2); // 2560 B

    prep_wfrag<<<24, 256, 0, stream>>>(Ws, wf);
    prep_tab<<<5, 256, 0, stream>>>(bs, gammas, betas, w_out, T);
    edge_fused<<<E_TOTAL/EPB, 256, 0, stream>>>(x, eidx, wf, T, b_out, out);
}

// Round 2
// 280.423 us; speedup vs baseline: 1.5614x; 1.5614x over previous
//
#include <hip/hip_runtime.h>

#define E_TOTAL   800000
#define HID       128
#define EPB       256
#define LN_EPS    1e-5f

typedef __attribute__((ext_vector_type(8)))  short bs8;
typedef __attribute__((ext_vector_type(16))) float fx16;

__device__ __forceinline__ unsigned short f2bf(float f) {
    union { float f; unsigned int i; } c; c.f = f;
    unsigned int r = c.i + 0x7FFFu + ((c.i >> 16) & 1u);
    return (unsigned short)(r >> 16);
}
__device__ __forceinline__ unsigned int cvt_pk_bf16(float a, float b) {
    unsigned int r;
    asm("v_cvt_pk_bf16_f32 %0, %1, %2" : "=v"(r) : "v"(a), "v"(b));
    return r;
}
__device__ __forceinline__ float fast_tanh(float x) {
    // tanh(x) = 1 - 2/(exp2(2*log2e*x)+1)
    float e = __builtin_amdgcn_exp2f(x * 2.8853900817779268f);
    float r = __builtin_amdgcn_rcpf(e + 1.0f);
    return fmaf(-2.0f, r, 1.0f);
}
__device__ __forceinline__ void ld16(const float* __restrict__ p, float* v) {
    #pragma unroll
    for (int q = 0; q < 4; ++q) {
        float4 t = reinterpret_cast<const float4*>(p)[q];
        v[q*4+0] = t.x; v[q*4+1] = t.y; v[q*4+2] = t.z; v[q*4+3] = t.w;
    }
}

// ---- prep 1: W -> MFMA A-fragment-linear bf16, A = W^T (M=fout, K=fin) ----
// frag fr = L*32 + rt*8 + ks ; lane l ; 8 bf16 = W[fi0+j][fo],
// fo = rt*32 + (l&31), fi0 = ks*16 + (l>>5)*8
__global__ void prep_wfrag(const float* __restrict__ Ws, unsigned short* __restrict__ wf) {
    int t = blockIdx.x * blockDim.x + threadIdx.x;
    if (t >= 3*4*8*64) return;
    int l  = t & 63;
    int fr = t >> 6;
    int ks = fr & 7;
    int rt = (fr >> 3) & 3;
    int L  = fr >> 5;
    int fo  = rt*32 + (l & 31);
    int fi0 = ks*16 + ((l >> 5) << 3);
    const float* src = Ws + L*HID*HID;
    unsigned short tmp[8];
    #pragma unroll
    for (int j = 0; j < 8; ++j) tmp[j] = f2bf(src[(fi0 + j)*HID + fo]);
    *reinterpret_cast<bs8*>(wf + t*8) = *reinterpret_cast<const bs8*>(tmp);
}

// ---- prep 2: constants reordered to C-fragment order, kept in f32 ----
// T[L][c][128] for c in {b,gamma,beta}, then wout[128] at offset 1152.
// within 128: idx = rt*32 + h*16 + reg ; fout = rt*32 + (reg&3) + 8*(reg>>2) + 4*h
__global__ void prep_tab(const float* __restrict__ bs, const float* __restrict__ gammas,
                         const float* __restrict__ betas, const float* __restrict__ w_out,
                         float* __restrict__ T) {
    int t = blockIdx.x * blockDim.x + threadIdx.x;
    if (t >= 1280) return;
    int reg = t & 15, h = (t >> 4) & 1, rt = (t >> 5) & 3;
    int fout = rt*32 + (reg & 3) + 8*(reg >> 2) + 4*h;
    float v;
    if (t < 1152) {
        int L = t / 384;
        int c = (t / 128) % 3;
        const float* src = (c == 0) ? bs : ((c == 1) ? gammas : betas);
        v = src[L*HID + fout];
    } else {
        v = w_out[fout];
    }
    T[t] = v;
}

// ---- fused main kernel: no cross-wave sharing -> zero barriers ----
__launch_bounds__(256, 2)
__global__ void edge_fused(const float* __restrict__ x,
                           const int* __restrict__ eidx,
                           const unsigned short* __restrict__ wf,
                           const float* __restrict__ T,
                           const float* __restrict__ b_out,
                           float* __restrict__ out)
{
    __shared__ __align__(16) unsigned short hA[EPB*HID];     // 64 KB, XOR-swizzled rows, wave-private regions
    __shared__ int idx_s[2*EPB];                             // 2 KB, wave-private regions

    const int t  = threadIdx.x;
    const int l  = t & 63;
    const int w  = t >> 6;
    const int eb = blockIdx.x * EPB;
    const int l31 = l & 31;
    const int h   = l >> 5;
    const int hh  = h << 4;

    idx_s[2*t]     = eidx[eb + t];
    idx_s[2*t + 1] = eidx[E_TOTAL + eb + t];

    // gather: wave w loads node rows for its own edges (rows w*128..w*128+127, row=2e+half)
    // 16 lanes cooperatively read one 256B node row (fully coalesced)
    #pragma unroll 8
    for (int i = 0; i < 32; ++i) {
        int r = w*128 + i*4 + (l >> 4);
        int node = idx_s[r];
        const float4 v = *(reinterpret_cast<const float4*>(x + node*64) + (l & 15));
        uint2 p;
        p.x = cvt_pk_bf16(v.x, v.y);
        p.y = cvt_pk_bf16(v.z, v.w);
        int e  = r >> 1;
        int cb = (r & 1)*128 + (l & 15)*8;
        *reinterpret_cast<uint2*>(reinterpret_cast<char*>(hA) + e*256 + (cb ^ ((e & 7) << 4))) = p;
    }

    const int e0 = w*64 + l31;          // this wave's two edge columns per lane
    const int e1 = e0 + 32;
    const int sz0 = (e0 & 7) << 4;
    const int sz1 = (e1 & 7) << 4;

    float o0 = 0.f, o1 = 0.f;

    for (int L = 0; L < 3; ++L) {
        const bs8* wbase = reinterpret_cast<const bs8*>(wf) + (L*32)*64 + l;
        const float* Tb = T + (L*3 + 0)*128 + hh;
        const float* Tg = T + (L*3 + 1)*128 + hh;
        const float* Te = T + (L*3 + 2)*128 + hh;

        // init acc with bias (folds the +b into MFMA C)
        fx16 acc[4][2];
        #pragma unroll
        for (int rt = 0; rt < 4; ++rt) {
            float bv[16]; ld16(Tb + rt*32, bv);
            #pragma unroll
            for (int j = 0; j < 16; ++j) { acc[rt][0][j] = bv[j]; acc[rt][1][j] = bv[j]; }
        }

        // Ct = W^T (A, from global/L1) @ H^T (B, from LDS): M=fout(4x32), N=edges(2x32), K=fin(8x16)
        #pragma unroll
        for (int ks = 0; ks < 8; ++ks) {
            const int cb = ks*32 + hh;
            bs8 b0 = *reinterpret_cast<const bs8*>(reinterpret_cast<const char*>(hA) + e0*256 + (cb ^ sz0));
            bs8 b1 = *reinterpret_cast<const bs8*>(reinterpret_cast<const char*>(hA) + e1*256 + (cb ^ sz1));
            #pragma unroll
            for (int rt = 0; rt < 4; ++rt) {
                bs8 a = wbase[(rt*8 + ks)*64];
                acc[rt][0] = __builtin_amdgcn_mfma_f32_32x32x16_bf16(a, b0, acc[rt][0], 0, 0, 0);
                acc[rt][1] = __builtin_amdgcn_mfma_f32_32x32x16_bf16(a, b1, acc[rt][1], 0, 0, 0);
            }
        }

        // ---- LN stats: in-register + one shfl_xor(32) ----
        float s0 = 0.f, s1 = 0.f, q0 = 0.f, q1 = 0.f;
        #pragma unroll
        for (int rt = 0; rt < 4; ++rt) {
            #pragma unroll
            for (int j = 0; j < 16; ++j) {
                float a0 = acc[rt][0][j];
                float a1 = acc[rt][1][j];
                s0 += a0; q0 = fmaf(a0, a0, q0);
                s1 += a1; q1 = fmaf(a1, a1, q1);
            }
        }
        s0 += __shfl_xor(s0, 32); q0 += __shfl_xor(q0, 32);
        s1 += __shfl_xor(s1, 32); q1 += __shfl_xor(q1, 32);
        const float mu0 = s0 * (1.f/128.f), mu1 = s1 * (1.f/128.f);
        const float r0 = rsqrtf(q0*(1.f/128.f) - mu0*mu0 + LN_EPS);
        const float r1 = rsqrtf(q1*(1.f/128.f) - mu1*mu1 + LN_EPS);
        const float nmur0 = -mu0 * r0, nmur1 = -mu1 * r1;

        if (L < 2) {
            #pragma unroll
            for (int rt = 0; rt < 4; ++rt) {
                float gv[16], ev[16];
                ld16(Tg + rt*32, gv);
                ld16(Te + rt*32, ev);
                float v0[16], v1[16];
                #pragma unroll
                for (int j = 0; j < 16; ++j) {
                    float t0 = fmaf(acc[rt][0][j], r0, nmur0);
                    float t1 = fmaf(acc[rt][1][j], r1, nmur1);
                    v0[j] = fast_tanh(fmaf(t0, gv[j], ev[j]));
                    v1[j] = fast_tanh(fmaf(t1, gv[j], ev[j]));
                }
                #pragma unroll
                for (int qd = 0; qd < 4; ++qd) {
                    uint2 p0, p1;
                    p0.x = cvt_pk_bf16(v0[qd*4+0], v0[qd*4+1]);
                    p0.y = cvt_pk_bf16(v0[qd*4+2], v0[qd*4+3]);
                    p1.x = cvt_pk_bf16(v1[qd*4+0], v1[qd*4+1]);
                    p1.y = cvt_pk_bf16(v1[qd*4+2], v1[qd*4+3]);
                    int cb = rt*64 + qd*16 + (h << 3);   // fout = rt*32 + 8*qd + 4*h + m
                    *reinterpret_cast<uint2*>(reinterpret_cast<char*>(hA) + e0*256 + (cb ^ sz0)) = p0;
                    *reinterpret_cast<uint2*>(reinterpret_cast<char*>(hA) + e1*256 + (cb ^ sz1)) = p1;
                }
            }
        } else {
            const float* Tw = T + 1152 + hh;
            #pragma unroll
            for (int rt = 0; rt < 4; ++rt) {
                float gv[16], ev[16], wv[16];
                ld16(Tg + rt*32, gv);
                ld16(Te + rt*32, ev);
                ld16(Tw + rt*32, wv);
                #pragma unroll
                for (int j = 0; j < 16; ++j) {
                    float t0 = fmaf(acc[rt][0][j], r0, nmur0);
                    float t1 = fmaf(acc[rt][1][j], r1, nmur1);
                    o0 = fmaf(fast_tanh(fmaf(t0, gv[j], ev[j])), wv[j], o0);
                    o1 = fmaf(fast_tanh(fmaf(t1, gv[j], ev[j])), wv[j], o1);
                }
            }
        }
    }

    o0 += __shfl_xor(o0, 32);
    o1 += __shfl_xor(o1, 32);
    if (l < 32) {
        const float bo = b_out[0];
        out[eb + w*64 + l]      = o0 + bo;
        out[eb + w*64 + 32 + l] = o1 + bo;
    }
}

extern "C" void kernel_launch(void* const* d_in, const int* in_sizes, int n_in,
                              void* d_out, int out_size, void* d_ws, size_t ws_size,
                              hipStream_t stream) {
    const float* x      = (const float*)d_in[0];
    const int*   eidx   = (const int*)d_in[1];
    const float* Ws     = (const float*)d_in[2];
    const float* bs     = (const float*)d_in[3];
    const float* gammas = (const float*)d_in[4];
    const float* betas  = (const float*)d_in[5];
    const float* w_out  = (const float*)d_in[6];
    const float* b_out  = (const float*)d_in[7];
    float* out = (float*)d_out;

    unsigned short* wf = (unsigned short*)d_ws;                 // 98304 B
    float* T = (float*)((char*)d_ws + 3*HID*HID*2);             // 5120 B

    prep_wfrag<<<24, 256, 0, stream>>>(Ws, wf);
    prep_tab<<<5, 256, 0, stream>>>(bs, gammas, betas, w_out, T);
    edge_fused<<<E_TOTAL/EPB, 256, 0, stream>>>(x, eidx, wf, T, b_out, out);
}

// Round 3
// 279.071 us; speedup vs baseline: 1.5690x; 1.0048x over previous
//
#include <hip/hip_runtime.h>

#define E_TOTAL   800000
#define HID       128
#define EPB       128            // 4 waves x 32 edges per block
#define LN_EPS    1e-5f

typedef __attribute__((ext_vector_type(8)))  short bs8;
typedef __attribute__((ext_vector_type(16))) float fx16;

__device__ __forceinline__ unsigned short f2bf(float f) {
    union { float f; unsigned int i; } c; c.f = f;
    unsigned int r = c.i + 0x7FFFu + ((c.i >> 16) & 1u);
    return (unsigned short)(r >> 16);
}
__device__ __forceinline__ unsigned int cvt_pk_bf16(float a, float b) {
    unsigned int r;
    asm("v_cvt_pk_bf16_f32 %0, %1, %2" : "=v"(r) : "v"(a), "v"(b));
    return r;
}
// swap: a' = {a.lo32lanes, b.lo32lanes}, b' = {a.hi32lanes, b.hi32lanes}
__device__ __forceinline__ void pswap(unsigned int &a, unsigned int &b) {
    asm("v_permlane32_swap_b32 %0, %1" : "+v"(a), "+v"(b));
}
__device__ __forceinline__ float fast_tanh(float x) {
    float e = __builtin_amdgcn_exp2f(x * 2.8853900817779268f);
    float r = __builtin_amdgcn_rcpf(e + 1.0f);
    return fmaf(-2.0f, r, 1.0f);
}
__device__ __forceinline__ void ld16(const float* __restrict__ p, float* v) {
    #pragma unroll
    for (int q = 0; q < 4; ++q) {
        float4 t = reinterpret_cast<const float4*>(p)[q];
        v[q*4+0] = t.x; v[q*4+1] = t.y; v[q*4+2] = t.z; v[q*4+3] = t.w;
    }
}

// ---- merged prep ----
// part A (t < 6144): W -> MFMA A-fragment-linear bf16, A = W^T (M=fout, K=fin)
//   frag fr = L*32 + rt*8 + ks ; lane l ; 8 bf16 = W[fi0+j][fo],
//   fo = rt*32 + (l&31), fi0 = ks*16 + (l>>5)*8
// part B (6144 <= t < 7424): constants in C-fragment order (f32):
//   T[L][c][128] c in {b,gamma,beta}; wout at 1152.
//   idx = rt*32 + h*16 + reg ; fout = rt*32 + (reg&3) + 8*(reg>>2) + 4*h
__global__ void prep(const float* __restrict__ Ws, const float* __restrict__ bs,
                     const float* __restrict__ gammas, const float* __restrict__ betas,
                     const float* __restrict__ w_out,
                     unsigned short* __restrict__ wf, float* __restrict__ T) {
    int t = blockIdx.x * blockDim.x + threadIdx.x;
    if (t < 6144) {
        int l  = t & 63;
        int fr = t >> 6;
        int ks = fr & 7;
        int rt = (fr >> 3) & 3;
        int L  = fr >> 5;
        int fo  = rt*32 + (l & 31);
        int fi0 = ks*16 + ((l >> 5) << 3);
        const float* src = Ws + L*HID*HID;
        unsigned short tmp[8];
        #pragma unroll
        for (int j = 0; j < 8; ++j) tmp[j] = f2bf(src[(fi0 + j)*HID + fo]);
        *reinterpret_cast<bs8*>(wf + t*8) = *reinterpret_cast<const bs8*>(tmp);
    } else if (t < 7424) {
        int u = t - 6144;
        int reg = u & 15, h = (u >> 4) & 1, rt = (u >> 5) & 3;
        int fout = rt*32 + (reg & 3) + 8*(reg >> 2) + 4*h;
        float v;
        if (u < 1152) {
            int L = u / 384;
            int c = (u / 128) % 3;
            const float* src = (c == 0) ? bs : ((c == 1) ? gammas : betas);
            v = src[L*HID + fout];
        } else {
            v = w_out[fout];
        }
        T[u] = v;
    }
}

// ---- fused main kernel: zero LDS, zero barriers, H stays in registers ----
// packed word wrd[rt][m] (bf16x2): features {Bm + 4h + 32rt, +1}, Bm = {0,2,8,10,16,18,24,26}
// B fragment for MFMA step ks (rows 16ks+8h..+7): 2 permlane32_swap on
// (wrd[ks>>1][mb], wrd[ks>>1][mb+2]) and (mb+1, mb+3), mb = (ks&1)*4.
__launch_bounds__(256, 3)
__global__ void edge_fused(const float* __restrict__ x,
                           const int* __restrict__ eidx,
                           const unsigned short* __restrict__ wf,
                           const float* __restrict__ T,
                           const float* __restrict__ b_out,
                           float* __restrict__ out)
{
    const int t   = threadIdx.x;
    const int l   = t & 63;
    const int w   = t >> 6;
    const int l31 = l & 31;
    const int h   = l >> 5;
    const int hh  = h << 4;
    const int e   = blockIdx.x * EPB + w*32 + l31;   // this lane's edge

    const int ns = eidx[e];
    const int nt = eidx[E_TOTAL + e];

    // layer-1 input: packed words straight from x (L2/L3-resident gather)
    unsigned int wrd[4][8];
    #pragma unroll
    for (int rt = 0; rt < 4; ++rt) {
        const float* src = (rt < 2) ? (x + ns*64 + rt*32) : (x + nt*64 + (rt-2)*32);
        #pragma unroll
        for (int g = 0; g < 4; ++g) {
            float4 v = *reinterpret_cast<const float4*>(src + g*8 + 4*h);
            wrd[rt][g*2+0] = cvt_pk_bf16(v.x, v.y);
            wrd[rt][g*2+1] = cvt_pk_bf16(v.z, v.w);
        }
    }

    float o0 = 0.f;

    #pragma unroll
    for (int L = 0; L < 3; ++L) {
        const bs8* wbase = reinterpret_cast<const bs8*>(wf) + (L*32)*64 + l;
        const float* Tb = T + (L*3 + 0)*128 + hh;
        const float* Tg = T + (L*3 + 1)*128 + hh;
        const float* Te = T + (L*3 + 2)*128 + hh;

        // init acc with bias (folds +b into MFMA C)
        fx16 acc[4];
        #pragma unroll
        for (int rt = 0; rt < 4; ++rt) {
            float bv[16]; ld16(Tb + rt*32, bv);
            #pragma unroll
            for (int j = 0; j < 16; ++j) acc[rt][j] = bv[j];
        }

        // Ct = W^T (A, global/L1) @ H^T (B, in-register via permlane)
        #pragma unroll
        for (int ks = 0; ks < 8; ++ks) {
            const int r  = ks >> 1;
            const int mb = (ks & 1) * 4;
            pswap(wrd[r][mb+0], wrd[r][mb+2]);
            pswap(wrd[r][mb+1], wrd[r][mb+3]);
            unsigned int bw[4] = { wrd[r][mb+0], wrd[r][mb+1], wrd[r][mb+2], wrd[r][mb+3] };
            bs8 b = *reinterpret_cast<const bs8*>(bw);
            #pragma unroll
            for (int rt = 0; rt < 4; ++rt) {
                bs8 a = wbase[(rt*8 + ks)*64];
                acc[rt] = __builtin_amdgcn_mfma_f32_32x32x16_bf16(a, b, acc[rt], 0, 0, 0);
            }
        }

        // LN stats: in-register + one shfl_xor(32) with the partner lane
        float s = 0.f, q = 0.f;
        #pragma unroll
        for (int rt = 0; rt < 4; ++rt) {
            #pragma unroll
            for (int j = 0; j < 16; ++j) {
                float a0 = acc[rt][j];
                s += a0; q = fmaf(a0, a0, q);
            }
        }
        s += __shfl_xor(s, 32);
        q += __shfl_xor(q, 32);
        const float mu   = s * (1.f/128.f);
        const float rr   = rsqrtf(q*(1.f/128.f) - mu*mu + LN_EPS);
        const float nmur = -mu * rr;

        if (L < 2) {
            #pragma unroll
            for (int rt = 0; rt < 4; ++rt) {
                float gv[16], ev[16];
                ld16(Tg + rt*32, gv);
                ld16(Te + rt*32, ev);
                #pragma unroll
                for (int m = 0; m < 8; ++m) {
                    float a0 = fmaf(fmaf(acc[rt][2*m],   rr, nmur), gv[2*m],   ev[2*m]);
                    float a1 = fmaf(fmaf(acc[rt][2*m+1], rr, nmur), gv[2*m+1], ev[2*m+1]);
                    wrd[rt][m] = cvt_pk_bf16(fast_tanh(a0), fast_tanh(a1));
                }
            }
        } else {
            const float* Tw = T + 1152 + hh;
            #pragma unroll
            for (int rt = 0; rt < 4; ++rt) {
                float gv[16], ev[16], wv[16];
                ld16(Tg + rt*32, gv);
                ld16(Te + rt*32, ev);
                ld16(Tw + rt*32, wv);
                #pragma unroll
                for (int j = 0; j < 16; ++j) {
                    float a0 = fmaf(fmaf(acc[rt][j], rr, nmur), gv[j], ev[j]);
                    o0 = fmaf(fast_tanh(a0), wv[j], o0);
                }
            }
        }
    }

    o0 += __shfl_xor(o0, 32);
    if (l < 32) out[e] = o0 + b_out[0];
}

extern "C" void kernel_launch(void* const* d_in, const int* in_sizes, int n_in,
                              void* d_out, int out_size, void* d_ws, size_t ws_size,
                              hipStream_t stream) {
    const float* x      = (const float*)d_in[0];
    const int*   eidx   = (const int*)d_in[1];
    const float* Ws     = (const float*)d_in[2];
    const float* bs     = (const float*)d_in[3];
    const float* gammas = (const float*)d_in[4];
    const float* betas  = (const float*)d_in[5];
    const float* w_out  = (const float*)d_in[6];
    const float* b_out  = (const float*)d_in[7];
    float* out = (float*)d_out;

    unsigned short* wf = (unsigned short*)d_ws;                 // 98304 B
    float* T = (float*)((char*)d_ws + 3*HID*HID*2);             // 5120 B

    prep<<<29, 256, 0, stream>>>(Ws, bs, gammas, betas, w_out, wf, T);
    edge_fused<<<E_TOTAL/EPB, 256, 0, stream>>>(x, eidx, wf, T, b_out, out);
}